// Round 7
// baseline (256.729 us; speedup 1.0000x reference)
//
#include <hip/hip_runtime.h>

// CapsNet dynamic routing — per-batch blocks, 2 launches.
// R7: x fragments live in REGISTERS for the whole kernel.
//   init: two 128c x 256i half-slabs of x converted fp32->fp16 through LDS
//         (row slab + transposed slab), loaded once into per-lane MFMA
//         B-fragments: yfrag[8] (x16[c][i]) and dfrag[8] (xT[i][c]).
//   3 iterations, all on-chip except W:
//     delta = u@xT (A: LDS ush, B: dfrag regs) ; b += delta+vb (registers)
//     softmax over j (register shfl) ; c -> LDS
//     y = c@x (A: LDS cs, B: yfrag regs) -> ysh
//     s[j,d] = dot(Wp stream from L2, ysh broadcast) ; v = squash(s)
//     u[j,c] = dot(Wd stream from L2, vsh) -> ush
//   Global traffic: x 64MB once, b_init 8MB, vout 2MB, W from per-XCD L2.

#define BSZ 256
#define CDIM 256
#define IDIM 256
#define JDIM 32
#define DDIM 64

typedef _Float16 f16x8 __attribute__((ext_vector_type(8)));
typedef _Float16 f16x4 __attribute__((ext_vector_type(4)));
typedef float f32x4 __attribute__((ext_vector_type(4)));

__device__ __forceinline__ float dot8(f16x8 a, f16x8 b, float acc) {
#if __has_builtin(__builtin_amdgcn_fdot2)
  acc = __builtin_amdgcn_fdot2(__builtin_shufflevector(a, a, 0, 1),
                               __builtin_shufflevector(b, b, 0, 1), acc, false);
  acc = __builtin_amdgcn_fdot2(__builtin_shufflevector(a, a, 2, 3),
                               __builtin_shufflevector(b, b, 2, 3), acc, false);
  acc = __builtin_amdgcn_fdot2(__builtin_shufflevector(a, a, 4, 5),
                               __builtin_shufflevector(b, b, 4, 5), acc, false);
  acc = __builtin_amdgcn_fdot2(__builtin_shufflevector(a, a, 6, 7),
                               __builtin_shufflevector(b, b, 6, 7), acc, false);
#else
  #pragma unroll
  for (int e = 0; e < 8; ++e) acc += (float)a[e] * (float)b[e];
#endif
  return acc;
}

// ---------------------------------------------------------------------------
// prep_w: grid 32 (block = j), block 256. Stage W_j in LDS, emit both packs.
// ---------------------------------------------------------------------------
__global__ __launch_bounds__(256) void prep_w(
    const float* __restrict__ W,   // [JDIM*DDIM][CDIM]
    _Float16* __restrict__ Wp,     // f16x8 [(j*32+g)*64+d] over c=8g..8g+7
    _Float16* __restrict__ Wd)     // f16x8 [(j*8+h)*256+c] over d=8h..8h+7
{
  __shared__ __align__(16) float Wsh[64 * 260];
  const int j = blockIdx.x, t = threadIdx.x;

  #pragma unroll
  for (int k = 0; k < 16; ++k) {
    const int q = k * 256 + t;
    const int row = q >> 6, c4 = (q & 63) * 4;
    *reinterpret_cast<f32x4*>(&Wsh[row * 260 + c4]) =
        *reinterpret_cast<const f32x4*>(&W[((size_t)j * 64 + row) * 256 + c4]);
  }
  __syncthreads();

  {
    const int d = t & 63;
    f16x8* out = reinterpret_cast<f16x8*>(Wp) + (size_t)j * 2048;
    #pragma unroll
    for (int k = 0; k < 8; ++k) {
      const int g = (t >> 6) + 4 * k;
      f32x4 a = *reinterpret_cast<const f32x4*>(&Wsh[d * 260 + 8 * g]);
      f32x4 bq = *reinterpret_cast<const f32x4*>(&Wsh[d * 260 + 8 * g + 4]);
      f16x8 h;
      h[0] = (_Float16)a[0]; h[1] = (_Float16)a[1];
      h[2] = (_Float16)a[2]; h[3] = (_Float16)a[3];
      h[4] = (_Float16)bq[0]; h[5] = (_Float16)bq[1];
      h[6] = (_Float16)bq[2]; h[7] = (_Float16)bq[3];
      out[g * 64 + d] = h;
    }
  }
  {
    const int c = t;
    f16x8* out = reinterpret_cast<f16x8*>(Wd) + (size_t)j * 2048;
    #pragma unroll
    for (int h = 0; h < 8; ++h) {
      f16x8 hh;
      #pragma unroll
      for (int e = 0; e < 8; ++e) hh[e] = (_Float16)Wsh[(8 * h + e) * 260 + c];
      out[h * 256 + c] = hh;
    }
  }
}

// ---------------------------------------------------------------------------
__global__ __launch_bounds__(1024) void caps_routing(
    const float* __restrict__ x,       // [BSZ][CDIM][IDIM] fp32
    const float* __restrict__ bias,    // [JDIM*DDIM] fp32
    const float* __restrict__ b_init,  // [BSZ][JDIM][IDIM] fp32
    const _Float16* __restrict__ Wp,
    const _Float16* __restrict__ Wd,
    float* __restrict__ vout)          // [BSZ][JDIM][DDIM]
{
  // LDS arena: init uses slabR (67584 B) + slabT (69632 B) = 137216 B.
  // steady state uses cs/ush/ysh/vsh/csum/vbs = 55 KB (time-disjoint).
  __shared__ __align__(16) char arena[137216];
  _Float16* slabR = reinterpret_cast<_Float16*>(arena);            // [128][264]
  _Float16* slabT = reinterpret_cast<_Float16*>(arena + 67584);    // [256][136]
  _Float16* cs    = reinterpret_cast<_Float16*>(arena);            // [32][264]
  _Float16* ush   = reinterpret_cast<_Float16*>(arena + 16896);    // [32][264]
  _Float16* ysh   = reinterpret_cast<_Float16*>(arena + 33792);    // [32][264]
  _Float16* vsh16 = reinterpret_cast<_Float16*>(arena + 50688);    // [32][64]
  float* csumsh   = reinterpret_cast<float*>(arena + 54784);       // [32]
  float* vbs      = reinterpret_cast<float*>(arena + 54912);       // [32]

  const int b = blockIdx.x, t = threadIdx.x;
  const int w = t >> 6, lane = t & 63, l15 = lane & 15, quad = lane >> 4;

  f16x8 yfrag[8];   // x16[c = w*16+l15][kk*32+quad*8 ..+8]
  f16x8 dfrag[8];   // xT [i = w*16+l15][kk*32+quad*8 ..+8]

  // ---- init: convert x through two LDS half-slabs, load frags ----
  for (int h = 0; h < 2; ++h) {
    #pragma unroll
    for (int q = 0; q < 2; ++q) {
      const int idx = q * 1024 + t;
      const int c4 = (idx >> 6) * 4;      // 0..124 (local c in half)
      const int i4 = (idx & 63) * 4;      // 0..252
      const float* src = x + (size_t)b * 65536 + (size_t)(h * 128 + c4) * 256 + i4;
      f32x4 v[4];
      #pragma unroll
      for (int s = 0; s < 4; ++s)
        v[s] = *reinterpret_cast<const f32x4*>(src + s * 256);
      #pragma unroll
      for (int s = 0; s < 4; ++s) {
        f16x4 hh;
        hh[0] = (_Float16)v[s][0]; hh[1] = (_Float16)v[s][1];
        hh[2] = (_Float16)v[s][2]; hh[3] = (_Float16)v[s][3];
        *reinterpret_cast<f16x4*>(&slabR[(c4 + s) * 264 + i4]) = hh;
      }
      #pragma unroll
      for (int m = 0; m < 4; ++m) {
        f16x4 hh;
        hh[0] = (_Float16)v[0][m]; hh[1] = (_Float16)v[1][m];
        hh[2] = (_Float16)v[2][m]; hh[3] = (_Float16)v[3][m];
        *reinterpret_cast<f16x4*>(&slabT[(i4 + m) * 136 + c4]) = hh;
      }
    }
    __syncthreads();
    if ((w >> 3) == h) {
      const int cloc = (w & 7) * 16 + l15;
      #pragma unroll
      for (int m = 0; m < 8; ++m)
        yfrag[m] = *reinterpret_cast<const f16x8*>(
            &slabR[cloc * 264 + quad * 8 + 32 * m]);
    }
    {
      const int ii = w * 16 + l15;
      #pragma unroll
      for (int kk = 0; kk < 4; ++kk)
        dfrag[h * 4 + kk] = *reinterpret_cast<const f16x8*>(
            &slabT[ii * 136 + kk * 32 + quad * 8]);
    }
    __syncthreads();
  }

  // ---- b -> registers, D-layout: j = mt*16+quad*4+rr, ii = w*16+l15 ----
  float breg[2][4];
  {
    const float* bp = b_init + (size_t)b * 8192;
    #pragma unroll
    for (int mt = 0; mt < 2; ++mt)
      #pragma unroll
      for (int rr = 0; rr < 4; ++rr)
        breg[mt][rr] = bp[(mt * 16 + quad * 4 + rr) * 256 + w * 16 + l15];
  }
  // per-wave bias cache (wave w owns j = w, w+16)
  const float bv0 = bias[w * 64 + lane];
  const float bv1 = bias[(w + 16) * 64 + lane];

  const f16x8* WpB = reinterpret_cast<const f16x8*>(Wp);
  const f16x8* WdB = reinterpret_cast<const f16x8*>(Wd);

  for (int r = 0; r < 3; ++r) {
    if (r) {
      // ---- delta[j,ii] = sum_c u[j,c] * xT[ii,c]  (B from dfrag regs) ----
      f32x4 acc0 = (f32x4){0.f, 0.f, 0.f, 0.f};
      f32x4 acc1 = (f32x4){0.f, 0.f, 0.f, 0.f};
      #pragma unroll
      for (int kk = 0; kk < 8; ++kk) {
        const int ko = kk * 32 + quad * 8;
        f16x8 a0 = *reinterpret_cast<const f16x8*>(&ush[l15 * 264 + ko]);
        f16x8 a1 = *reinterpret_cast<const f16x8*>(&ush[(16 + l15) * 264 + ko]);
        acc0 = __builtin_amdgcn_mfma_f32_16x16x32_f16(a0, dfrag[kk], acc0, 0, 0, 0);
        acc1 = __builtin_amdgcn_mfma_f32_16x16x32_f16(a1, dfrag[kk], acc1, 0, 0, 0);
      }
      #pragma unroll
      for (int rr = 0; rr < 4; ++rr) {
        breg[0][rr] += acc0[rr] + vbs[quad * 4 + rr];
        breg[1][rr] += acc1[rr] + vbs[16 + quad * 4 + rr];
      }
    }

    if (t < 32) csumsh[t] = 0.f;

    // ---- softmax over j (registers + shfl across quads) ----
    float cc[2][4];
    {
      float m = breg[0][0];
      #pragma unroll
      for (int mt = 0; mt < 2; ++mt)
        #pragma unroll
        for (int rr = 0; rr < 4; ++rr) m = fmaxf(m, breg[mt][rr]);
      m = fmaxf(m, __shfl_xor(m, 16));
      m = fmaxf(m, __shfl_xor(m, 32));
      float s = 0.f;
      #pragma unroll
      for (int mt = 0; mt < 2; ++mt)
        #pragma unroll
        for (int rr = 0; rr < 4; ++rr) {
          float e = __expf(breg[mt][rr] - m);
          cc[mt][rr] = e; s += e;
        }
      s += __shfl_xor(s, 16);
      s += __shfl_xor(s, 32);
      const float rinv = 1.f / s;
      const int ii = w * 16 + l15;
      #pragma unroll
      for (int mt = 0; mt < 2; ++mt)
        #pragma unroll
        for (int rr = 0; rr < 4; ++rr) {
          const float cv = cc[mt][rr] * rinv;
          cc[mt][rr] = cv;
          cs[(mt * 16 + quad * 4 + rr) * 264 + ii] = (_Float16)cv;
        }
    }
    __syncthreads();  // cs visible, csumsh zeroed

    // ---- csum[j] atomics ----
    #pragma unroll
    for (int mt = 0; mt < 2; ++mt)
      #pragma unroll
      for (int rr = 0; rr < 4; ++rr) {
        float pj = cc[mt][rr];
        pj += __shfl_xor(pj, 1);
        pj += __shfl_xor(pj, 2);
        pj += __shfl_xor(pj, 4);
        pj += __shfl_xor(pj, 8);
        if (l15 == 0) atomicAdd(&csumsh[mt * 16 + quad * 4 + rr], pj);
      }

    // ---- y[j,c] = sum_i c[j,i] * x16[c,i]  (B from yfrag regs) ----
    {
      f32x4 acy0 = (f32x4){0.f, 0.f, 0.f, 0.f};
      f32x4 acy1 = (f32x4){0.f, 0.f, 0.f, 0.f};
      #pragma unroll
      for (int kk = 0; kk < 8; ++kk) {
        const int ko = kk * 32 + quad * 8;
        f16x8 a0 = *reinterpret_cast<const f16x8*>(&cs[l15 * 264 + ko]);
        f16x8 a1 = *reinterpret_cast<const f16x8*>(&cs[(16 + l15) * 264 + ko]);
        acy0 = __builtin_amdgcn_mfma_f32_16x16x32_f16(a0, yfrag[kk], acy0, 0, 0, 0);
        acy1 = __builtin_amdgcn_mfma_f32_16x16x32_f16(a1, yfrag[kk], acy1, 0, 0, 0);
      }
      const int cp = w * 16 + l15;
      #pragma unroll
      for (int rr = 0; rr < 4; ++rr) {
        ysh[(quad * 4 + rr) * 264 + cp] = (_Float16)acy0[rr];
        ysh[(16 + quad * 4 + rr) * 264 + cp] = (_Float16)acy1[rr];
      }
    }
    __syncthreads();  // ysh + csumsh complete; ush reads (delta) done

    // ---- per-j s / squash / u (wave w owns j = w, w+16) ----
    #pragma unroll
    for (int jq = 0; jq < 2; ++jq) {
      const int jj = w + jq * 16;
      const float biasv = jq ? bv1 : bv0;
      const f16x8* wrow = WpB + (size_t)jj * 2048 + lane;   // + g*64
      const _Float16* yr = &ysh[jj * 264];
      float sacc = 0.f;
      #pragma unroll 4
      for (int g = 0; g < 32; ++g)
        sacc = dot8(wrow[g * 64], *reinterpret_cast<const f16x8*>(&yr[g * 8]), sacc);
      sacc += biasv * csumsh[jj];

      float n2 = sacc * sacc;
      n2 += __shfl_xor(n2, 1);
      n2 += __shfl_xor(n2, 2);
      n2 += __shfl_xor(n2, 4);
      n2 += __shfl_xor(n2, 8);
      n2 += __shfl_xor(n2, 16);
      n2 += __shfl_xor(n2, 32);
      const float sc = sqrtf(n2) / (1.f + n2);
      const float vv = sacc * sc;

      if (r == 2) {
        vout[((size_t)b * 32 + jj) * 64 + lane] = vv;
      } else {
        vsh16[jj * 64 + lane] = (_Float16)vv;
        float vbp = vv * biasv;
        vbp += __shfl_xor(vbp, 1);
        vbp += __shfl_xor(vbp, 2);
        vbp += __shfl_xor(vbp, 4);
        vbp += __shfl_xor(vbp, 8);
        vbp += __shfl_xor(vbp, 16);
        vbp += __shfl_xor(vbp, 32);
        if (lane == 0) vbs[jj] = vbp;

        // u[jj,c] = sum_d v[jj,d] * W[jj,d,c]   (lane = c base)
        float ua[4] = {0.f, 0.f, 0.f, 0.f};
        const f16x8* wd = WdB + (size_t)jj * 2048;
        #pragma unroll
        for (int h = 0; h < 8; ++h) {
          f16x8 vvv = *reinterpret_cast<const f16x8*>(&vsh16[jj * 64 + h * 8]);
          #pragma unroll
          for (int k = 0; k < 4; ++k)
            ua[k] = dot8(wd[h * 256 + lane + 64 * k], vvv, ua[k]);
        }
        #pragma unroll
        for (int k = 0; k < 4; ++k)
          ush[jj * 264 + lane + 64 * k] = (_Float16)ua[k];
      }
    }
    if (r < 2) __syncthreads();  // ush + vbs visible; cs/ysh reusable
  }
}

// ---------------------------------------------------------------------------
extern "C" void kernel_launch(void* const* d_in, const int* in_sizes, int n_in,
                              void* d_out, int out_size, void* d_ws, size_t ws_size,
                              hipStream_t stream) {
  (void)in_sizes; (void)n_in; (void)out_size; (void)ws_size;
  const float* x      = (const float*)d_in[0];
  const float* W      = (const float*)d_in[1];
  const float* bias   = (const float*)d_in[2];
  const float* b_init = (const float*)d_in[3];
  char* ws = (char*)d_ws;

  _Float16* Wp = (_Float16*)(ws);                 // 1 MiB
  _Float16* Wd = (_Float16*)(ws + (1u << 20));    // 1 MiB
  float* vout  = (float*)d_out;

  prep_w<<<32, 256, 0, stream>>>(W, Wp, Wd);
  caps_routing<<<BSZ, 1024, 0, stream>>>(x, bias, b_init, Wp, Wd, vout);
}

// Round 8
// 253.929 us; speedup vs baseline: 1.0110x; 1.0110x over previous
//
#include <hip/hip_runtime.h>

// CapsNet dynamic routing — per-batch blocks, 2 launches.
// R8 = R7 + __launch_bounds__(1024, 4): R7's x-fragments-in-registers plan
// was silently spilled to scratch (VGPR capped at 64; WRITE_SIZE showed
// 124 MB of spill stores). 4 waves/EU -> 128-VGPR budget -> frags stay
// in registers for real this time.
//   init: x converted fp32->fp16 via two LDS half-slabs into per-lane MFMA
//         B-fragments: yfrag[8] (x16[c][i]) and dfrag[8] (xT[i][c]).
//   3 iterations, all on-chip except W (streamed from per-XCD L2):
//     delta = u@xT (MFMA) ; b += delta+vb (registers)
//     softmax over j (register shfl) ; c -> LDS ; y = c@x (MFMA) -> ysh
//     s[j,d] = dot8(Wp, ysh) ; v = squash(s) ; u[j,c] = dot8(Wd, v) -> ush

#define BSZ 256
#define CDIM 256
#define IDIM 256
#define JDIM 32
#define DDIM 64

typedef _Float16 f16x8 __attribute__((ext_vector_type(8)));
typedef _Float16 f16x4 __attribute__((ext_vector_type(4)));
typedef float f32x4 __attribute__((ext_vector_type(4)));

__device__ __forceinline__ float dot8(f16x8 a, f16x8 b, float acc) {
#if __has_builtin(__builtin_amdgcn_fdot2)
  acc = __builtin_amdgcn_fdot2(__builtin_shufflevector(a, a, 0, 1),
                               __builtin_shufflevector(b, b, 0, 1), acc, false);
  acc = __builtin_amdgcn_fdot2(__builtin_shufflevector(a, a, 2, 3),
                               __builtin_shufflevector(b, b, 2, 3), acc, false);
  acc = __builtin_amdgcn_fdot2(__builtin_shufflevector(a, a, 4, 5),
                               __builtin_shufflevector(b, b, 4, 5), acc, false);
  acc = __builtin_amdgcn_fdot2(__builtin_shufflevector(a, a, 6, 7),
                               __builtin_shufflevector(b, b, 6, 7), acc, false);
#else
  #pragma unroll
  for (int e = 0; e < 8; ++e) acc += (float)a[e] * (float)b[e];
#endif
  return acc;
}

// ---------------------------------------------------------------------------
// prep_w: grid 32 (block = j), block 256. Stage W_j in LDS, emit both packs.
// ---------------------------------------------------------------------------
__global__ __launch_bounds__(256) void prep_w(
    const float* __restrict__ W,   // [JDIM*DDIM][CDIM]
    _Float16* __restrict__ Wp,     // f16x8 [(j*32+g)*64+d] over c=8g..8g+7
    _Float16* __restrict__ Wd)     // f16x8 [(j*8+h)*256+c] over d=8h..8h+7
{
  __shared__ __align__(16) float Wsh[64 * 260];
  const int j = blockIdx.x, t = threadIdx.x;

  #pragma unroll
  for (int k = 0; k < 16; ++k) {
    const int q = k * 256 + t;
    const int row = q >> 6, c4 = (q & 63) * 4;
    *reinterpret_cast<f32x4*>(&Wsh[row * 260 + c4]) =
        *reinterpret_cast<const f32x4*>(&W[((size_t)j * 64 + row) * 256 + c4]);
  }
  __syncthreads();

  {
    const int d = t & 63;
    f16x8* out = reinterpret_cast<f16x8*>(Wp) + (size_t)j * 2048;
    #pragma unroll
    for (int k = 0; k < 8; ++k) {
      const int g = (t >> 6) + 4 * k;
      f32x4 a = *reinterpret_cast<const f32x4*>(&Wsh[d * 260 + 8 * g]);
      f32x4 bq = *reinterpret_cast<const f32x4*>(&Wsh[d * 260 + 8 * g + 4]);
      f16x8 h;
      h[0] = (_Float16)a[0]; h[1] = (_Float16)a[1];
      h[2] = (_Float16)a[2]; h[3] = (_Float16)a[3];
      h[4] = (_Float16)bq[0]; h[5] = (_Float16)bq[1];
      h[6] = (_Float16)bq[2]; h[7] = (_Float16)bq[3];
      out[g * 64 + d] = h;
    }
  }
  {
    const int c = t;
    f16x8* out = reinterpret_cast<f16x8*>(Wd) + (size_t)j * 2048;
    #pragma unroll
    for (int h = 0; h < 8; ++h) {
      f16x8 hh;
      #pragma unroll
      for (int e = 0; e < 8; ++e) hh[e] = (_Float16)Wsh[(8 * h + e) * 260 + c];
      out[h * 256 + c] = hh;
    }
  }
}

// ---------------------------------------------------------------------------
__global__ __launch_bounds__(1024, 4) void caps_routing(
    const float* __restrict__ x,       // [BSZ][CDIM][IDIM] fp32
    const float* __restrict__ bias,    // [JDIM*DDIM] fp32
    const float* __restrict__ b_init,  // [BSZ][JDIM][IDIM] fp32
    const _Float16* __restrict__ Wp,
    const _Float16* __restrict__ Wd,
    float* __restrict__ vout)          // [BSZ][JDIM][DDIM]
{
  // LDS arena: init uses slabR (67584 B) + slabT (69632 B) = 137216 B.
  // steady state uses cs/ush/ysh/vsh/csum/vbs = 55 KB (time-disjoint).
  __shared__ __align__(16) char arena[137216];
  _Float16* slabR = reinterpret_cast<_Float16*>(arena);            // [128][264]
  _Float16* slabT = reinterpret_cast<_Float16*>(arena + 67584);    // [256][136]
  _Float16* cs    = reinterpret_cast<_Float16*>(arena);            // [32][264]
  _Float16* ush   = reinterpret_cast<_Float16*>(arena + 16896);    // [32][264]
  _Float16* ysh   = reinterpret_cast<_Float16*>(arena + 33792);    // [32][264]
  _Float16* vsh16 = reinterpret_cast<_Float16*>(arena + 50688);    // [32][64]
  float* csumsh   = reinterpret_cast<float*>(arena + 54784);       // [32]
  float* vbs      = reinterpret_cast<float*>(arena + 54912);       // [32]

  const int b = blockIdx.x, t = threadIdx.x;
  const int w = t >> 6, lane = t & 63, l15 = lane & 15, quad = lane >> 4;

  f16x8 yfrag[8];   // x16[c = w*16+l15][kk*32+quad*8 ..+8]
  f16x8 dfrag[8];   // xT [i = w*16+l15][kk*32+quad*8 ..+8]

  // ---- init: convert x through two LDS half-slabs, load frags ----
  for (int h = 0; h < 2; ++h) {
    #pragma unroll
    for (int q = 0; q < 2; ++q) {
      const int idx = q * 1024 + t;
      const int c4 = (idx >> 6) * 4;      // 0..124 (local c in half)
      const int i4 = (idx & 63) * 4;      // 0..252
      const float* src = x + (size_t)b * 65536 + (size_t)(h * 128 + c4) * 256 + i4;
      f32x4 v[4];
      #pragma unroll
      for (int s = 0; s < 4; ++s)
        v[s] = *reinterpret_cast<const f32x4*>(src + s * 256);
      #pragma unroll
      for (int s = 0; s < 4; ++s) {
        f16x4 hh;
        hh[0] = (_Float16)v[s][0]; hh[1] = (_Float16)v[s][1];
        hh[2] = (_Float16)v[s][2]; hh[3] = (_Float16)v[s][3];
        *reinterpret_cast<f16x4*>(&slabR[(c4 + s) * 264 + i4]) = hh;
      }
      #pragma unroll
      for (int m = 0; m < 4; ++m) {
        f16x4 hh;
        hh[0] = (_Float16)v[0][m]; hh[1] = (_Float16)v[1][m];
        hh[2] = (_Float16)v[2][m]; hh[3] = (_Float16)v[3][m];
        *reinterpret_cast<f16x4*>(&slabT[(i4 + m) * 136 + c4]) = hh;
      }
    }
    __syncthreads();
    if ((w >> 3) == h) {
      const int cloc = (w & 7) * 16 + l15;
      #pragma unroll
      for (int m = 0; m < 8; ++m)
        yfrag[m] = *reinterpret_cast<const f16x8*>(
            &slabR[cloc * 264 + quad * 8 + 32 * m]);
    }
    {
      const int ii = w * 16 + l15;
      #pragma unroll
      for (int kk = 0; kk < 4; ++kk)
        dfrag[h * 4 + kk] = *reinterpret_cast<const f16x8*>(
            &slabT[ii * 136 + kk * 32 + quad * 8]);
    }
    __syncthreads();
  }

  // ---- b -> registers, D-layout: j = mt*16+quad*4+rr, ii = w*16+l15 ----
  float breg[2][4];
  {
    const float* bp = b_init + (size_t)b * 8192;
    #pragma unroll
    for (int mt = 0; mt < 2; ++mt)
      #pragma unroll
      for (int rr = 0; rr < 4; ++rr)
        breg[mt][rr] = bp[(mt * 16 + quad * 4 + rr) * 256 + w * 16 + l15];
  }
  // per-wave bias cache (wave w owns j = w, w+16)
  const float bv0 = bias[w * 64 + lane];
  const float bv1 = bias[(w + 16) * 64 + lane];

  const f16x8* WpB = reinterpret_cast<const f16x8*>(Wp);
  const f16x8* WdB = reinterpret_cast<const f16x8*>(Wd);

  for (int r = 0; r < 3; ++r) {
    if (r) {
      // ---- delta[j,ii] = sum_c u[j,c] * xT[ii,c]  (B from dfrag regs) ----
      f32x4 acc0 = (f32x4){0.f, 0.f, 0.f, 0.f};
      f32x4 acc1 = (f32x4){0.f, 0.f, 0.f, 0.f};
      #pragma unroll
      for (int kk = 0; kk < 8; ++kk) {
        const int ko = kk * 32 + quad * 8;
        f16x8 a0 = *reinterpret_cast<const f16x8*>(&ush[l15 * 264 + ko]);
        f16x8 a1 = *reinterpret_cast<const f16x8*>(&ush[(16 + l15) * 264 + ko]);
        acc0 = __builtin_amdgcn_mfma_f32_16x16x32_f16(a0, dfrag[kk], acc0, 0, 0, 0);
        acc1 = __builtin_amdgcn_mfma_f32_16x16x32_f16(a1, dfrag[kk], acc1, 0, 0, 0);
      }
      #pragma unroll
      for (int rr = 0; rr < 4; ++rr) {
        breg[0][rr] += acc0[rr] + vbs[quad * 4 + rr];
        breg[1][rr] += acc1[rr] + vbs[16 + quad * 4 + rr];
      }
    }

    if (t < 32) csumsh[t] = 0.f;

    // ---- softmax over j (registers + shfl across quads) ----
    float cc[2][4];
    {
      float m = breg[0][0];
      #pragma unroll
      for (int mt = 0; mt < 2; ++mt)
        #pragma unroll
        for (int rr = 0; rr < 4; ++rr) m = fmaxf(m, breg[mt][rr]);
      m = fmaxf(m, __shfl_xor(m, 16));
      m = fmaxf(m, __shfl_xor(m, 32));
      float s = 0.f;
      #pragma unroll
      for (int mt = 0; mt < 2; ++mt)
        #pragma unroll
        for (int rr = 0; rr < 4; ++rr) {
          float e = __expf(breg[mt][rr] - m);
          cc[mt][rr] = e; s += e;
        }
      s += __shfl_xor(s, 16);
      s += __shfl_xor(s, 32);
      const float rinv = 1.f / s;
      const int ii = w * 16 + l15;
      #pragma unroll
      for (int mt = 0; mt < 2; ++mt)
        #pragma unroll
        for (int rr = 0; rr < 4; ++rr) {
          const float cv = cc[mt][rr] * rinv;
          cc[mt][rr] = cv;
          cs[(mt * 16 + quad * 4 + rr) * 264 + ii] = (_Float16)cv;
        }
    }
    __syncthreads();  // cs visible, csumsh zeroed

    // ---- csum[j] atomics ----
    #pragma unroll
    for (int mt = 0; mt < 2; ++mt)
      #pragma unroll
      for (int rr = 0; rr < 4; ++rr) {
        float pj = cc[mt][rr];
        pj += __shfl_xor(pj, 1);
        pj += __shfl_xor(pj, 2);
        pj += __shfl_xor(pj, 4);
        pj += __shfl_xor(pj, 8);
        if (l15 == 0) atomicAdd(&csumsh[mt * 16 + quad * 4 + rr], pj);
      }

    // ---- y[j,c] = sum_i c[j,i] * x16[c,i]  (B from yfrag regs) ----
    {
      f32x4 acy0 = (f32x4){0.f, 0.f, 0.f, 0.f};
      f32x4 acy1 = (f32x4){0.f, 0.f, 0.f, 0.f};
      #pragma unroll
      for (int kk = 0; kk < 8; ++kk) {
        const int ko = kk * 32 + quad * 8;
        f16x8 a0 = *reinterpret_cast<const f16x8*>(&cs[l15 * 264 + ko]);
        f16x8 a1 = *reinterpret_cast<const f16x8*>(&cs[(16 + l15) * 264 + ko]);
        acy0 = __builtin_amdgcn_mfma_f32_16x16x32_f16(a0, yfrag[kk], acy0, 0, 0, 0);
        acy1 = __builtin_amdgcn_mfma_f32_16x16x32_f16(a1, yfrag[kk], acy1, 0, 0, 0);
      }
      const int cp = w * 16 + l15;
      #pragma unroll
      for (int rr = 0; rr < 4; ++rr) {
        ysh[(quad * 4 + rr) * 264 + cp] = (_Float16)acy0[rr];
        ysh[(16 + quad * 4 + rr) * 264 + cp] = (_Float16)acy1[rr];
      }
    }
    __syncthreads();  // ysh + csumsh complete; ush reads (delta) done

    // ---- per-j s / squash / u (wave w owns j = w, w+16) ----
    #pragma unroll
    for (int jq = 0; jq < 2; ++jq) {
      const int jj = w + jq * 16;
      const float biasv = jq ? bv1 : bv0;
      const f16x8* wrow = WpB + (size_t)jj * 2048 + lane;   // + g*64
      const _Float16* yr = &ysh[jj * 264];
      float sacc = 0.f;
      #pragma unroll 4
      for (int g = 0; g < 32; ++g)
        sacc = dot8(wrow[g * 64], *reinterpret_cast<const f16x8*>(&yr[g * 8]), sacc);
      sacc += biasv * csumsh[jj];

      float n2 = sacc * sacc;
      n2 += __shfl_xor(n2, 1);
      n2 += __shfl_xor(n2, 2);
      n2 += __shfl_xor(n2, 4);
      n2 += __shfl_xor(n2, 8);
      n2 += __shfl_xor(n2, 16);
      n2 += __shfl_xor(n2, 32);
      const float sc = sqrtf(n2) / (1.f + n2);
      const float vv = sacc * sc;

      if (r == 2) {
        vout[((size_t)b * 32 + jj) * 64 + lane] = vv;
      } else {
        vsh16[jj * 64 + lane] = (_Float16)vv;
        float vbp = vv * biasv;
        vbp += __shfl_xor(vbp, 1);
        vbp += __shfl_xor(vbp, 2);
        vbp += __shfl_xor(vbp, 4);
        vbp += __shfl_xor(vbp, 8);
        vbp += __shfl_xor(vbp, 16);
        vbp += __shfl_xor(vbp, 32);
        if (lane == 0) vbs[jj] = vbp;

        // u[jj,c] = sum_d v[jj,d] * W[jj,d,c]   (lane = c base)
        float ua[4] = {0.f, 0.f, 0.f, 0.f};
        const f16x8* wd = WdB + (size_t)jj * 2048;
        #pragma unroll
        for (int h = 0; h < 8; ++h) {
          f16x8 vvv = *reinterpret_cast<const f16x8*>(&vsh16[jj * 64 + h * 8]);
          #pragma unroll
          for (int k = 0; k < 4; ++k)
            ua[k] = dot8(wd[h * 256 + lane + 64 * k], vvv, ua[k]);
        }
        #pragma unroll
        for (int k = 0; k < 4; ++k)
          ush[jj * 264 + lane + 64 * k] = (_Float16)ua[k];
      }
    }
    if (r < 2) __syncthreads();  // ush + vbs visible; cs/ysh reusable
  }
}

// ---------------------------------------------------------------------------
extern "C" void kernel_launch(void* const* d_in, const int* in_sizes, int n_in,
                              void* d_out, int out_size, void* d_ws, size_t ws_size,
                              hipStream_t stream) {
  (void)in_sizes; (void)n_in; (void)out_size; (void)ws_size;
  const float* x      = (const float*)d_in[0];
  const float* W      = (const float*)d_in[1];
  const float* bias   = (const float*)d_in[2];
  const float* b_init = (const float*)d_in[3];
  char* ws = (char*)d_ws;

  _Float16* Wp = (_Float16*)(ws);                 // 1 MiB
  _Float16* Wd = (_Float16*)(ws + (1u << 20));    // 1 MiB
  float* vout  = (float*)d_out;

  prep_w<<<32, 256, 0, stream>>>(W, Wp, Wd);
  caps_routing<<<BSZ, 1024, 0, stream>>>(x, bias, b_init, Wp, Wd, vout);
}